// Round 1
// baseline (181.698 us; speedup 1.0000x reference)
//
#include <hip/hip_runtime.h>

// Problem constants (from reference)
constexpr int L  = 250;   // layers
constexpr int T  = 600;   // traces
constexpr int A  = 30;    // angles
constexpr int AP = 32;    // padded angle dim (LDS leading dim, float4-aligned)

// One block per trace t. Phase 1: compute ref[k][a] (Zoeppritz Rpp via Cramer,
// f64 determinants) into LDS. Phase 2: cal[l][a] = sum_k wm[l][k]*ref[k][a],
// each thread owns 4 angles x 8 layers (32 fp32 accumulators).
// LDS = 250*32*4 = 32000 B + 256 B => ~3-4 blocks/CU.
__global__ __launch_bounds__(256, 3)
void zoeppritz_fused(const float* __restrict__ vp,
                     const float* __restrict__ vs,
                     const float* __restrict__ rho,
                     const float* __restrict__ theta,
                     const float* __restrict__ wm,
                     float* __restrict__ out)
{
    __shared__ float ref_s[L * AP];
    __shared__ float sth_s[AP];
    __shared__ float cth_s[AP];

    const int tid = threadIdx.x;
    const int t   = blockIdx.x;

    if (tid < AP) {
        const float th = (tid < A) ? theta[tid] : 0.0f;
        sth_s[tid] = sinf(th);
        cth_s[tid] = cosf(th);
    }
    __syncthreads();

    // ---- Phase 1: Zoeppritz Rpp per (interface k, angle a) ----
    // idx & 31 = a (so 32 consecutive lanes share k -> broadcast loads)
    for (int idx = tid; idx < L * AP; idx += 256) {
        const int k = idx >> 5;
        const int a = idx & 31;
        float rpp = 0.0f;
        if (a < A && k < L - 1) {
            const float a1 = vp[k * T + t];
            const float a2 = vp[(k + 1) * T + t];
            const float b1 = vs[k * T + t];
            const float b2 = vs[(k + 1) * T + t];
            const float r1 = rho[k * T + t];
            const float r2 = rho[(k + 1) * T + t];

            const float sth = sth_s[a];
            const float cth = cth_s[a];
            const float p   = sth / a1;                 // ray parameter

            // sin/cos of refracted / converted angles without arcsin:
            const float s2  = fminf(fmaxf(p * a2, -1.0f), 1.0f);
            const float c2  = sqrtf(fmaxf(1.0f - s2 * s2, 0.0f));
            const float sp1 = fminf(fmaxf(p * b1, -1.0f), 1.0f);
            const float cp1 = sqrtf(fmaxf(1.0f - sp1 * sp1, 0.0f));
            const float sp2 = fminf(fmaxf(p * b2, -1.0f), 1.0f);
            const float cp2 = sqrtf(fmaxf(1.0f - sp2 * sp2, 0.0f));

            const float rb1 = r1 * b1, rb2 = r2 * b2;
            const float k1  = 1.0f - 2.0f * sp1 * sp1;
            const float k2  = 1.0f - 2.0f * sp2 * sp2;
            const float q1  = rb1 * k1;
            const float q2  = rb2 * k2;
            const float P1  = r1 * a1 * k1;
            const float P2  = r2 * a2 * k2;
            const float S1  = 2.0f * rb1 * sp1 * cp1;   // r1*b1*sin(2*phi1)
            const float S2  = 2.0f * rb2 * sp2 * cp2;
            const float g1  = 2.0f * rb1 * sp1 * cth;   // row2 col0
            const float g2  = 2.0f * rb2 * sp2 * c2;    // row2 col2

            // M (row-major), N column 0
            const double m00 = -sth, m01 = -cp1, m02 = s2,  m03 = cp2;
            const double m10 =  cth, m11 = -sp1, m12 = c2,  m13 = -sp2;
            const double m20 =  g1,  m21 =  q1,  m22 = g2,  m23 = q2;
            const double m30 = -P1,  m31 =  S1,  m32 = P2,  m33 = -S2;
            const double n0  =  sth, n1 = cth,   n2  = g1,  n3  = P1;

            // det via 2x2 minors (rows 0-1 => s*, rows 2-3 => c*)
            const double s0v = m00 * m11 - m10 * m01;
            const double s1v = m00 * m12 - m10 * m02;
            const double s2v = m00 * m13 - m10 * m03;
            const double s3v = m01 * m12 - m11 * m02;
            const double s4v = m01 * m13 - m11 * m03;
            const double s5v = m02 * m13 - m12 * m03;
            const double c0v = m20 * m31 - m30 * m21;
            const double c1v = m20 * m32 - m30 * m22;
            const double c2vv= m20 * m33 - m30 * m23;
            const double c3v = m21 * m32 - m31 * m22;
            const double c4v = m21 * m33 - m31 * m23;
            const double c5v = m22 * m33 - m32 * m23;
            const double detM = s0v*c5v - s1v*c4v + s2v*c3v
                              + s3v*c2vv - s4v*c1v + s5v*c0v;
            // Cramer: column 0 of M replaced by N[:,0] (only s0-2, c0-2 change)
            const double t0 = n0 * m11 - n1 * m01;
            const double t1 = n0 * m12 - n1 * m02;
            const double t2 = n0 * m13 - n1 * m03;
            const double u0 = n2 * m31 - n3 * m21;
            const double u1 = n2 * m32 - n3 * m22;
            const double u2 = n2 * m33 - n3 * m23;
            const double detN = t0*c5v - t1*c4v + t2*c3v
                              + s3v*u2 - s4v*u1 + s5v*u0;

            rpp = (float)detN / (float)detM;
        }
        ref_s[idx] = rpp;   // k == L-1 row and a >= 30 stay 0
    }
    __syncthreads();

    // ---- Phase 2: cal[l][a] = sum_k wm[l*250+k] * ref[k][a] ----
    const int aq = tid & 7;     // angle quad 0..7 -> a = 4*aq .. 4*aq+3
    const int lq = tid >> 3;    // 0..31 -> l = 8*lq .. 8*lq+7

    float acc[8][4];
#pragma unroll
    for (int i = 0; i < 8; ++i)
#pragma unroll
        for (int j = 0; j < 4; ++j) acc[i][j] = 0.0f;

    int lofs[8];
#pragma unroll
    for (int i = 0; i < 8; ++i) {
        const int l = lq * 8 + i;
        lofs[i] = (l < L ? l : L - 1) * L;   // clamp: duplicate work, discarded at store
    }

    const float4* __restrict__ rp = (const float4*)ref_s;  // rp[k*8 + aq]
    for (int k = 0; k < L; ++k) {
        const float4 rv = rp[k * (AP / 4) + aq];   // 16B aligned, conflict-free
#pragma unroll
        for (int i = 0; i < 8; ++i) {
            const float w = wm[lofs[i] + k];
            acc[i][0] = fmaf(w, rv.x, acc[i][0]);
            acc[i][1] = fmaf(w, rv.y, acc[i][1]);
            acc[i][2] = fmaf(w, rv.z, acc[i][2]);
            acc[i][3] = fmaf(w, rv.w, acc[i][3]);
        }
    }

    // ---- Store: out[t][l][a], fp32 ----
    float* outt = out + (size_t)t * (L * A);
    const int a0 = aq * 4;
    const int nj = (a0 + 4 <= A) ? 4 : (A - a0);   // aq==7 -> 2 angles only
#pragma unroll
    for (int i = 0; i < 8; ++i) {
        const int l = lq * 8 + i;
        if (l < L) {
            for (int j = 0; j < nj; ++j)
                outt[l * A + a0 + j] = acc[i][j];
        }
    }
}

extern "C" void kernel_launch(void* const* d_in, const int* in_sizes, int n_in,
                              void* d_out, int out_size, void* d_ws, size_t ws_size,
                              hipStream_t stream) {
    (void)in_sizes; (void)n_in; (void)out_size; (void)d_ws; (void)ws_size;
    const float* vp    = (const float*)d_in[0];
    const float* vs    = (const float*)d_in[1];
    const float* rho   = (const float*)d_in[2];
    const float* theta = (const float*)d_in[3];
    const float* wm    = (const float*)d_in[4];
    float* out = (float*)d_out;

    zoeppritz_fused<<<dim3(T), dim3(256), 0, stream>>>(vp, vs, rho, theta, wm, out);
}

// Round 2
// 143.667 us; speedup vs baseline: 1.2647x; 1.2647x over previous
//
#include <hip/hip_runtime.h>

// Problem constants (from reference)
constexpr int L  = 250;   // layers
constexpr int T  = 600;   // traces
constexpr int A  = 30;    // angles
constexpr int AP = 32;    // padded angle dim (float4-aligned)
constexpr int KP = 256;   // padded k dim in workspace (power of 2 -> shift indexing)
constexpr int TRACE_STRIDE = KP * AP;   // 8192 floats per trace in ws

// ---------------- Kernel A: ref[t][k][a] = Zoeppritz Rpp ----------------
// One thread per padded element. idx bits: [4:0]=a, [12:5]=k, [13+]=t.
// ws layout: ref_g[t*8192 + k*32 + a]; k>=249 or a>=30 -> 0.
__global__ __launch_bounds__(256)
void zoep_ref_kernel(const float* __restrict__ vp,
                     const float* __restrict__ vs,
                     const float* __restrict__ rho,
                     const float* __restrict__ theta,
                     float* __restrict__ ref_g)
{
    const int idx = blockIdx.x * 256 + threadIdx.x;
    const int a = idx & 31;
    const int k = (idx >> 5) & (KP - 1);
    const int t = idx >> 13;

    float rpp = 0.0f;
    if (a < A && k < L - 1) {
        const float th  = theta[a];
        const float sth = sinf(th);
        const float cth = cosf(th);

        const float a1 = vp[k * T + t];
        const float a2 = vp[(k + 1) * T + t];
        const float b1 = vs[k * T + t];
        const float b2 = vs[(k + 1) * T + t];
        const float r1 = rho[k * T + t];
        const float r2 = rho[(k + 1) * T + t];

        const float p   = sth / a1;   // ray parameter

        // sin/cos of refracted/converted angles without arcsin:
        const float s2  = fminf(fmaxf(p * a2, -1.0f), 1.0f);
        const float c2  = sqrtf(fmaxf(1.0f - s2 * s2, 0.0f));
        const float sp1 = fminf(fmaxf(p * b1, -1.0f), 1.0f);
        const float cp1 = sqrtf(fmaxf(1.0f - sp1 * sp1, 0.0f));
        const float sp2 = fminf(fmaxf(p * b2, -1.0f), 1.0f);
        const float cp2 = sqrtf(fmaxf(1.0f - sp2 * sp2, 0.0f));

        const float rb1 = r1 * b1, rb2 = r2 * b2;
        const float k1  = 1.0f - 2.0f * sp1 * sp1;
        const float k2  = 1.0f - 2.0f * sp2 * sp2;
        const float q1  = rb1 * k1;
        const float q2  = rb2 * k2;
        const float P1  = r1 * a1 * k1;
        const float P2  = r2 * a2 * k2;
        const float S1  = 2.0f * rb1 * sp1 * cp1;
        const float S2  = 2.0f * rb2 * sp2 * cp2;
        const float g1  = 2.0f * rb1 * sp1 * cth;
        const float g2  = 2.0f * rb2 * sp2 * c2;

        // M (row-major), N column 0 — f64 determinants (Cramer) for stability
        const double m00 = -sth, m01 = -cp1, m02 = s2,  m03 = cp2;
        const double m10 =  cth, m11 = -sp1, m12 = c2,  m13 = -sp2;
        const double m20 =  g1,  m21 =  q1,  m22 = g2,  m23 = q2;
        const double m30 = -P1,  m31 =  S1,  m32 = P2,  m33 = -S2;
        const double n0  =  sth, n1 = cth,   n2  = g1,  n3  = P1;

        const double s0v = m00 * m11 - m10 * m01;
        const double s1v = m00 * m12 - m10 * m02;
        const double s2v = m00 * m13 - m10 * m03;
        const double s3v = m01 * m12 - m11 * m02;
        const double s4v = m01 * m13 - m11 * m03;
        const double s5v = m02 * m13 - m12 * m03;
        const double c0v = m20 * m31 - m30 * m21;
        const double c1v = m20 * m32 - m30 * m22;
        const double c2vv= m20 * m33 - m30 * m23;
        const double c3v = m21 * m32 - m31 * m22;
        const double c4v = m21 * m33 - m31 * m23;
        const double c5v = m22 * m33 - m32 * m23;
        const double detM = s0v*c5v - s1v*c4v + s2v*c3v
                          + s3v*c2vv - s4v*c1v + s5v*c0v;
        const double t0 = n0 * m11 - n1 * m01;
        const double t1 = n0 * m12 - n1 * m02;
        const double t2 = n0 * m13 - n1 * m03;
        const double u0 = n2 * m31 - n3 * m21;
        const double u1 = n2 * m32 - n3 * m22;
        const double u2 = n2 * m33 - n3 * m23;
        const double detN = t0*c5v - t1*c4v + t2*c3v
                          + s3v*u2 - s4v*u1 + s5v*u0;

        rpp = (float)detN / (float)detM;
    }
    ref_g[idx] = rpp;
}

// ---------------- Kernel B: out[t][l][a] = sum_k wm[l][k] * ref[t][k][a] ----
// grid = T * 2 l-tiles of 128. block = 256. Thread owns 4 layers x 4 angles.
// K staged in LDS slabs of 64 (8 KB) with coalesced float4 loads.
__global__ __launch_bounds__(256)
void zoep_gemm_kernel(const float* __restrict__ wm,
                      const float* __restrict__ ref_g,
                      float* __restrict__ out)
{
    __shared__ float rs[64 * AP];          // 8 KB k-slab of ref
    float4* rs4 = (float4*)rs;

    const int tid  = threadIdx.x;
    const int b    = blockIdx.x;
    const int t    = b >> 1;
    const int l0   = (b & 1) * 128;

    const int aq = tid & 7;                // angle quad: a = 4*aq..4*aq+3
    const int lg = tid >> 3;               // 0..31; layers l0+lg+32*i

    const float* ref_t = ref_g + (size_t)t * TRACE_STRIDE;
    const float4* rg4  = (const float4*)ref_t;   // rg4[k*8 + aq]

    float acc[4][4];
#pragma unroll
    for (int i = 0; i < 4; ++i)
#pragma unroll
        for (int j = 0; j < 4; ++j) acc[i][j] = 0.0f;

    int lidx[4]; bool lvalid[4];
#pragma unroll
    for (int i = 0; i < 4; ++i) {
        const int l = l0 + lg + 32 * i;
        lvalid[i] = (l < L);
        lidx[i]   = (lvalid[i] ? l : L - 1) * L;   // clamped wm row offset
    }

    for (int k0 = 0; k0 < L; k0 += 64) {
        // stage 64x32 ref slab (coalesced, 16 B/lane)
        __syncthreads();
        rs4[tid]       = rg4[(k0 << 3) + tid];
        rs4[tid + 256] = rg4[(k0 << 3) + tid + 256];
        __syncthreads();

        const int kmax = (L - k0 < 64) ? (L - k0) : 64;
        const float* w0 = wm + lidx[0] + k0;
        const float* w1 = wm + lidx[1] + k0;
        const float* w2 = wm + lidx[2] + k0;
        const float* w3 = wm + lidx[3] + k0;

#pragma unroll 4
        for (int kk = 0; kk < kmax; ++kk) {
            const float4 rv = rs4[kk * 8 + aq];    // 8-way broadcast, conflict-free
            const float wv0 = w0[kk];
            const float wv1 = w1[kk];
            const float wv2 = w2[kk];
            const float wv3 = w3[kk];
            acc[0][0] = fmaf(wv0, rv.x, acc[0][0]);
            acc[0][1] = fmaf(wv0, rv.y, acc[0][1]);
            acc[0][2] = fmaf(wv0, rv.z, acc[0][2]);
            acc[0][3] = fmaf(wv0, rv.w, acc[0][3]);
            acc[1][0] = fmaf(wv1, rv.x, acc[1][0]);
            acc[1][1] = fmaf(wv1, rv.y, acc[1][1]);
            acc[1][2] = fmaf(wv1, rv.z, acc[1][2]);
            acc[1][3] = fmaf(wv1, rv.w, acc[1][3]);
            acc[2][0] = fmaf(wv2, rv.x, acc[2][0]);
            acc[2][1] = fmaf(wv2, rv.y, acc[2][1]);
            acc[2][2] = fmaf(wv2, rv.z, acc[2][2]);
            acc[2][3] = fmaf(wv2, rv.w, acc[2][3]);
            acc[3][0] = fmaf(wv3, rv.x, acc[3][0]);
            acc[3][1] = fmaf(wv3, rv.y, acc[3][1]);
            acc[3][2] = fmaf(wv3, rv.z, acc[3][2]);
            acc[3][3] = fmaf(wv3, rv.w, acc[3][3]);
        }
    }

    // store out[t][l][a] (fp32); aq==7 has only angles 28,29
    float* outt = out + (size_t)t * (L * A);
    const int a0 = aq * 4;
    const int nj = (a0 + 4 <= A) ? 4 : (A - a0);
#pragma unroll
    for (int i = 0; i < 4; ++i) {
        if (lvalid[i]) {
            const int l = l0 + lg + 32 * i;
            float* o = outt + l * A + a0;
            for (int j = 0; j < nj; ++j) o[j] = acc[i][j];
        }
    }
}

extern "C" void kernel_launch(void* const* d_in, const int* in_sizes, int n_in,
                              void* d_out, int out_size, void* d_ws, size_t ws_size,
                              hipStream_t stream) {
    (void)in_sizes; (void)n_in; (void)out_size; (void)ws_size;
    const float* vp    = (const float*)d_in[0];
    const float* vs    = (const float*)d_in[1];
    const float* rho   = (const float*)d_in[2];
    const float* theta = (const float*)d_in[3];
    const float* wm    = (const float*)d_in[4];
    float* out   = (float*)d_out;
    float* ref_g = (float*)d_ws;    // T * 8192 floats = 19.66 MB

    const int blocksA = (T * TRACE_STRIDE) / 256;   // 19200
    zoep_ref_kernel<<<dim3(blocksA), dim3(256), 0, stream>>>(vp, vs, rho, theta, ref_g);
    zoep_gemm_kernel<<<dim3(T * 2), dim3(256), 0, stream>>>(wm, ref_g, out);
}